// Round 4
// baseline (1173.006 us; speedup 1.0000x reference)
//
#include <hip/hip_runtime.h>
#include <hip/hip_bf16.h>
#include <math.h>

#define BB 2
#define NCAM 6
#define NQ 900
#define NC 256
#define BN (BB*NCAM)        // 12
#define NROW (BB*NQ)        // 1800

// Load float input element i; f=1 -> buffer is bf16, f=0 -> fp32.
__device__ __forceinline__ float ldT(const void* p, long i, int f){
  if (f){
    unsigned short u = ((const unsigned short*)p)[i];
    union{unsigned int v; float fl;} x; x.v = ((unsigned int)u)<<16; return x.fl;
  }
  return ((const float*)p)[i];
}

// ---------------- prep: dtype sniff + mask normalize + extrinsic inverse ----------------
// Workspace written: inv_ext 768B @0, dflag 4B @1024, mask_int 7200B @2048  (<10KB)
__global__ void prep_kernel(const unsigned char* __restrict__ refraw,
                            const void* __restrict__ ext,
                            const unsigned char* __restrict__ mask_raw,
                            int* __restrict__ flag_out,
                            float* __restrict__ inv_out,
                            int* __restrict__ mask_out){
  __shared__ int s_nonalign, s_gt1, s_bf, s_flag;
  int t = threadIdx.x;
  if (t==0){
    s_nonalign=0; s_gt1=0; s_bf=0;
    // dtype sniff on reference_points (U[0,1]): bf16 high bytes are exponent
    // bytes in [0x30,0x40); fp32 bytes at pos 1 mod 4 are uniform mantissa.
    int cnt=0;
    for (int i=1;i<64;i+=4){
      unsigned char b = refraw[i];
      if (b>=0x30 && b<0x40) cnt++;
    }
    s_flag = (cnt>=12) ? 1 : 0;
    *flag_out = s_flag;
  }
  __syncthreads();
  int f_na=0, f_gt=0, f_bf=0;
  for (int i=t;i<NROW;i+=blockDim.x){
    unsigned char b = mask_raw[i];
    if ((i&3)!=0 && b!=0) f_na=1;
    if (b>1) f_gt=1;
    if ((i&3)==1 && b==0x3f) f_bf=1;
  }
  if (f_na) atomicOr(&s_nonalign,1);
  if (f_gt) atomicOr(&s_gt1,1);
  if (f_bf) atomicOr(&s_bf,1);
  __syncthreads();
  int fmt; // 0=int32, 1=uint8(bool), 2=bf16, 3=fp32
  if (!s_nonalign) fmt=0;
  else if (!s_gt1)  fmt=1;
  else              fmt = s_bf ? 2 : 3;
  for (int i=t;i<NROW;i+=blockDim.x){
    int v;
    if (fmt==0)      v = (((const int*)mask_raw)[i]            != 0);
    else if (fmt==1) v = (mask_raw[i]                          != 0);
    else if (fmt==2) v = (((const unsigned short*)mask_raw)[i] != 0);
    else             v = (((const float*)mask_raw)[i]          != 0.0f);
    mask_out[i]=v;
  }
  // invert 12 4x4 matrices, fp64 Gauss-Jordan with partial pivot
  if (t < BN){
    int f = s_flag;
    double a[4][8];
    for(int i=0;i<4;i++){
      for(int j=0;j<4;j++) a[i][j] = (double)ldT(ext, t*16+i*4+j, f);
      for(int j=0;j<4;j++) a[i][4+j] = (i==j)?1.0:0.0;
    }
    for(int col=0;col<4;col++){
      int piv=col; double best=fabs(a[col][col]);
      for(int r=col+1;r<4;r++){ double v=fabs(a[r][col]); if(v>best){best=v;piv=r;} }
      if(piv!=col) for(int j=0;j<8;j++){ double tmp=a[col][j]; a[col][j]=a[piv][j]; a[piv][j]=tmp; }
      double id = 1.0/a[col][col];
      for(int j=0;j<8;j++) a[col][j]*=id;
      for(int r=0;r<4;r++) if(r!=col){
        double fc=a[r][col];
        for(int j=0;j<8;j++) a[r][j]-=fc*a[col][j];
      }
    }
    for(int i=0;i<4;i++)for(int j=0;j<4;j++){
      float v=(float)a[i][4+j];
      if (isnan(v)) v=0.f;
      else if (isinf(v)) v = (v>0.f)?1e6f:-1e6f;
      inv_out[t*16+i*4+j]=v;
    }
  }
}

// ---------------- fused: project + sample + 3 matvecs + max + epilogue ----------------
__global__ __launch_bounds__(256) void fused_kernel(
    const void* __restrict__ query, const void* __restrict__ refpts,
    const void* __restrict__ intr,
    const void* __restrict__ f0, const void* __restrict__ f1,
    const void* __restrict__ f2, const void* __restrict__ f3,
    const void* __restrict__ Wq, const void* __restrict__ bq,
    const void* __restrict__ Wv, const void* __restrict__ bv,
    const void* __restrict__ Wo, const void* __restrict__ bo,
    const float* __restrict__ inv_ext, const int* __restrict__ mask_int,
    const int* __restrict__ flag, float* __restrict__ out){
  __shared__ float s_q[NC];
  __shared__ float s_ms[NCAM][NC];
  __shared__ float s_fused[NC];
  __shared__ float px_s[NCAM], py_s[NCAM];
  __shared__ int   iv_s[NCAM];

  int row = blockIdx.x;           // b*NQ + q
  int b = row/NQ;
  int t = threadIdx.x;
  int f = *flag;
  int m = mask_int[row];

  // stage query row
  s_q[t] = ldT(query, (long)row*NC+t, f);

  // threads 0..5: project this query point through camera t
  if (t < NCAM){
    float h0 = ldT(refpts, (long)row*3+0, f)*102.4f - 51.2f;
    float h1 = ldT(refpts, (long)row*3+1, f)*102.4f - 51.2f;
    float h2 = ldT(refpts, (long)row*3+2, f)*102.4f - 51.2f;
    if (m){ h0=-1000.f; h1=-1000.f; h2=-1000.f; }
    const float* M = inv_ext + (b*NCAM+t)*16;
    float c0 = M[0]*h0 + M[1]*h1 + M[2]*h2 + M[3];
    float c1 = M[4]*h0 + M[5]*h1 + M[6]*h2 + M[7];
    float c2 = M[8]*h0 + M[9]*h1 + M[10]*h2 + M[11];
    float depth = c2;
    if (isnan(depth)) depth = 10.f;
    else if (isinf(depth)) depth = (depth>0)?100.f:-100.f;
    int iv = (depth < 1.5f);
    float ds = fmaxf(depth, 1.5f);
    float pc0=c0/ds, pc1=c1/ds, pc2=c2/ds;
    long kb = (long)(b*NCAM+t)*9;
    float ix = ldT(intr,kb+0,f)*pc0 + ldT(intr,kb+1,f)*pc1 + ldT(intr,kb+2,f)*pc2;
    float iy = ldT(intr,kb+3,f)*pc0 + ldT(intr,kb+4,f)*pc1 + ldT(intr,kb+5,f)*pc2;
    px_s[t] = fminf(fmaxf(ix,-3000.f),3000.f);
    py_s[t] = fminf(fmaxf(iy,-3000.f),3000.f);
    iv_s[t] = iv;
  }
  __syncthreads();

  // bilinear sampling: thread t = channel, all 6 cameras, 4 levels
  const void* fbase[4] = {f0,f1,f2,f3};
  const int Hs[4]={112,56,28,14};
  const int Ws[4]={200,100,50,25};
  for (int n=0;n<NCAM;n++){
    float x = px_s[n], y = py_s[n];
    int iv = iv_s[n];
    float acc = 0.f;
    #pragma unroll
    for(int l=0;l<4;l++){
      const int W=Ws[l], H=Hs[l];
      float fx = x * ((float)W/800.0f);
      float fy = y * ((float)H/448.0f);
      float gx = fx/(W-1.0f)*2.0f-1.0f;
      float gy = fy/(H-1.0f)*2.0f-1.0f;
      gx = fminf(fmaxf(gx,-10.f),10.f);
      gy = fminf(fmaxf(gy,-10.f),10.f);
      if (iv){ gx=-100.f; gy=-100.f; }
      float pxx=(gx+1.f)*0.5f*(W-1.f);
      float pyy=(gy+1.f)*0.5f*(H-1.f);
      float x0f=floorf(pxx), y0f=floorf(pyy);
      int x0=(int)x0f, y0=(int)y0f;
      float wx1=pxx-x0f, wy1=pyy-y0f;
      float wx0=1.f-wx1, wy0=1.f-wy1;
      long base = (long)((b*NCAM+n)*NC+t)*H*W;
      if (y0>=0 && y0<H){
        if (x0>=0   && x0<W  ) acc += wx0*wy0*ldT(fbase[l], base+(long)y0*W+x0,   f);
        if (x0+1>=0 && x0+1<W) acc += wx1*wy0*ldT(fbase[l], base+(long)y0*W+x0+1, f);
      }
      if (y0+1>=0 && y0+1<H){
        if (x0>=0   && x0<W  ) acc += wx0*wy1*ldT(fbase[l], base+(long)(y0+1)*W+x0,   f);
        if (x0+1>=0 && x0+1<W) acc += wx1*wy1*ldT(fbase[l], base+(long)(y0+1)*W+x0+1, f);
      }
    }
    s_ms[n][t] = acc*0.25f;
  }

  // q projection: dot Wq row t with s_q
  float qv = 0.f;
  {
    long rb = (long)t*NC;
    #pragma unroll 8
    for (int k=0;k<NC;k++) qv = fmaf(ldT(Wq, rb+k, f), s_q[k], qv);
    qv += ldT(bq, t, f);
  }
  __syncthreads();   // s_ms ready

  // v projection + max over cameras
  float acc[NCAM];
  #pragma unroll
  for(int n=0;n<NCAM;n++) acc[n]=0.f;
  {
    long rb = (long)t*NC;
    #pragma unroll 4
    for (int k=0;k<NC;k++){
      float wf = ldT(Wv, rb+k, f);
      #pragma unroll
      for(int n=0;n<NCAM;n++) acc[n] = fmaf(wf, s_ms[n][k], acc[n]);
    }
  }
  float sv = acc[0];
  #pragma unroll
  for(int n=1;n<NCAM;n++) sv = fmaxf(sv, acc[n]);
  sv += ldT(bv, t, f);

  s_fused[t] = fmaxf(qv+sv, 0.f) + qv;
  __syncthreads();

  // output projection
  float o = 0.f;
  {
    long rb = (long)t*NC;
    #pragma unroll 8
    for (int k=0;k<NC;k++) o = fmaf(ldT(Wo, rb+k, f), s_fused[k], o);
    o += ldT(bo, t, f);
  }
  if (m) o = 0.f;
  out[(long)row*NC+t] = o;   // fp32 output — reference returns float32
}

extern "C" void kernel_launch(void* const* d_in, const int* in_sizes, int n_in,
                              void* d_out, int out_size, void* d_ws, size_t ws_size,
                              hipStream_t stream){
  const void* query  = d_in[0];
  const void* refpts = d_in[1];
  const unsigned char* mask_raw = (const unsigned char*)d_in[2];
  const void* intr   = d_in[3];
  const void* ext    = d_in[4];
  const void* f0     = d_in[5];
  const void* f1     = d_in[6];
  const void* f2     = d_in[7];
  const void* f3     = d_in[8];
  const void* Wq     = d_in[9];
  const void* bq     = d_in[10];
  const void* Wv     = d_in[11];
  const void* bv     = d_in[12];
  const void* Wo     = d_in[13];
  const void* bo     = d_in[14];

  char* ws = (char*)d_ws;
  float* inv_ext  = (float*)(ws + 0);       // 768 B
  int*   dflag    = (int*)  (ws + 1024);    // 4 B
  int*   mask_int = (int*)  (ws + 2048);    // 7200 B  (total <10 KB)

  hipLaunchKernelGGL(prep_kernel, dim3(1), dim3(256), 0, stream,
                     (const unsigned char*)refpts, ext, mask_raw, dflag, inv_ext, mask_int);
  hipLaunchKernelGGL(fused_kernel, dim3(NROW), dim3(256), 0, stream,
                     query, refpts, intr, f0, f1, f2, f3,
                     Wq, bq, Wv, bv, Wo, bo,
                     inv_ext, mask_int, dflag, (float*)d_out);
}

// Round 5
// 702.430 us; speedup vs baseline: 1.6699x; 1.6699x over previous
//
#include <hip/hip_runtime.h>
#include <hip/hip_bf16.h>
#include <math.h>

#define BB 2
#define NCAM 6
#define NQ 900
#define NC 256
#define BN (BB*NCAM)        // 12
#define NROW (BB*NQ)        // 1800

typedef float f4 __attribute__((ext_vector_type(4)));
typedef unsigned short u16x4 __attribute__((ext_vector_type(4)));

__device__ __forceinline__ float u2f(unsigned short u){
  union{unsigned int v; float fl;} x; x.v=((unsigned int)u)<<16; return x.fl;
}

template<int F>
__device__ __forceinline__ float ld1(const void* p, long i){
  if (F) return u2f(((const unsigned short*)p)[i]);
  return ((const float*)p)[i];
}
template<int F>
__device__ __forceinline__ f4 ld4(const void* p, long i){ // i = element index, %4==0
  if (F){
    u16x4 u = *(const u16x4*)((const unsigned short*)p + i);
    f4 r; r.x=u2f(u.x); r.y=u2f(u.y); r.z=u2f(u.z); r.w=u2f(u.w); return r;
  }
  return *(const f4*)((const float*)p + i);
}

// ---------------- prep: dtype sniff + mask normalize + extrinsic inverse ----------------
// Workspace written: inv_ext 768B @0, dflag 4B @1024, mask_int 7200B @2048  (<10KB)
__global__ void prep_kernel(const unsigned char* __restrict__ refraw,
                            const void* __restrict__ ext,
                            const unsigned char* __restrict__ mask_raw,
                            int* __restrict__ flag_out,
                            float* __restrict__ inv_out,
                            int* __restrict__ mask_out){
  __shared__ int s_nonalign, s_gt1, s_bf, s_flag;
  int t = threadIdx.x;
  if (t==0){
    s_nonalign=0; s_gt1=0; s_bf=0;
    int cnt=0;
    for (int i=1;i<64;i+=4){
      unsigned char b = refraw[i];
      if (b>=0x30 && b<0x40) cnt++;
    }
    s_flag = (cnt>=12) ? 1 : 0;
    *flag_out = s_flag;
  }
  __syncthreads();
  int f_na=0, f_gt=0, f_bf=0;
  for (int i=t;i<NROW;i+=blockDim.x){
    unsigned char b = mask_raw[i];
    if ((i&3)!=0 && b!=0) f_na=1;
    if (b>1) f_gt=1;
    if ((i&3)==1 && b==0x3f) f_bf=1;
  }
  if (f_na) atomicOr(&s_nonalign,1);
  if (f_gt) atomicOr(&s_gt1,1);
  if (f_bf) atomicOr(&s_bf,1);
  __syncthreads();
  int fmt; // 0=int32, 1=uint8(bool), 2=bf16, 3=fp32
  if (!s_nonalign) fmt=0;
  else if (!s_gt1)  fmt=1;
  else              fmt = s_bf ? 2 : 3;
  for (int i=t;i<NROW;i+=blockDim.x){
    int v;
    if (fmt==0)      v = (((const int*)mask_raw)[i]            != 0);
    else if (fmt==1) v = (mask_raw[i]                          != 0);
    else if (fmt==2) v = (((const unsigned short*)mask_raw)[i] != 0);
    else             v = (((const float*)mask_raw)[i]          != 0.0f);
    mask_out[i]=v;
  }
  if (t < BN){
    int f = s_flag;
    double a[4][8];
    for(int i=0;i<4;i++){
      for(int j=0;j<4;j++) a[i][j] = (double)(f? u2f(((const unsigned short*)ext)[t*16+i*4+j])
                                               : ((const float*)ext)[t*16+i*4+j]);
      for(int j=0;j<4;j++) a[i][4+j] = (i==j)?1.0:0.0;
    }
    for(int col=0;col<4;col++){
      int piv=col; double best=fabs(a[col][col]);
      for(int r=col+1;r<4;r++){ double v=fabs(a[r][col]); if(v>best){best=v;piv=r;} }
      if(piv!=col) for(int j=0;j<8;j++){ double tmp=a[col][j]; a[col][j]=a[piv][j]; a[piv][j]=tmp; }
      double id = 1.0/a[col][col];
      for(int j=0;j<8;j++) a[col][j]*=id;
      for(int r=0;r<4;r++) if(r!=col){
        double fc=a[r][col];
        for(int j=0;j<8;j++) a[r][j]-=fc*a[col][j];
      }
    }
    for(int i=0;i<4;i++)for(int j=0;j<4;j++){
      float v=(float)a[i][4+j];
      if (isnan(v)) v=0.f;
      else if (isinf(v)) v = (v>0.f)?1e6f:-1e6f;
      inv_out[t*16+i*4+j]=v;
    }
  }
}

// ---------------- fused kernel ----------------
struct SharedMem {
  float q[NC];
  float ms[NCAM][NC];
  float fus[NC];
  float px[NCAM], py[NCAM];
  int   iv[NCAM];
  int   off[NCAM*4][4];
  float wgt[NCAM*4][4];
};

template<int F>
__device__ __forceinline__ void fused_body(
    const void* __restrict__ query, const void* __restrict__ refpts,
    const void* __restrict__ intr,
    const void* __restrict__ f0, const void* __restrict__ f1,
    const void* __restrict__ f2, const void* __restrict__ f3,
    const void* __restrict__ Wq, const void* __restrict__ bq,
    const void* __restrict__ Wv, const void* __restrict__ bv,
    const void* __restrict__ Wo, const void* __restrict__ bo,
    const float* __restrict__ inv_ext, const int* __restrict__ mask_int,
    float* __restrict__ out, SharedMem& sm){
  int row = blockIdx.x;           // b*NQ + q
  int b = row/NQ;
  int t = threadIdx.x;
  int m = mask_int[row];

  // phase 1: stage query row; threads 0..5 project through camera t
  sm.q[t] = ld1<F>(query, (long)row*NC+t);
  if (t < NCAM){
    float h0 = ld1<F>(refpts,(long)row*3+0)*102.4f - 51.2f;
    float h1 = ld1<F>(refpts,(long)row*3+1)*102.4f - 51.2f;
    float h2 = ld1<F>(refpts,(long)row*3+2)*102.4f - 51.2f;
    if (m){ h0=-1000.f; h1=-1000.f; h2=-1000.f; }
    const float* M = inv_ext + (b*NCAM+t)*16;
    float c0 = M[0]*h0 + M[1]*h1 + M[2]*h2 + M[3];
    float c1 = M[4]*h0 + M[5]*h1 + M[6]*h2 + M[7];
    float c2 = M[8]*h0 + M[9]*h1 + M[10]*h2 + M[11];
    float depth = c2;
    if (isnan(depth)) depth = 10.f;
    else if (isinf(depth)) depth = (depth>0)?100.f:-100.f;
    int iv = (depth < 1.5f);
    float ds = fmaxf(depth, 1.5f);
    float pc0=c0/ds, pc1=c1/ds, pc2=c2/ds;
    long kb = (long)(b*NCAM+t)*9;
    float ix = ld1<F>(intr,kb+0)*pc0 + ld1<F>(intr,kb+1)*pc1 + ld1<F>(intr,kb+2)*pc2;
    float iy = ld1<F>(intr,kb+3)*pc0 + ld1<F>(intr,kb+4)*pc1 + ld1<F>(intr,kb+5)*pc2;
    sm.px[t] = fminf(fmaxf(ix,-3000.f),3000.f);
    sm.py[t] = fminf(fmaxf(iy,-3000.f),3000.f);
    sm.iv[t] = iv;
  }
  __syncthreads();

  // phase 2: threads 0..23 precompute per-(cam,level) corner offsets + weights
  if (t < NCAM*4){
    const int Ws_[4]={200,100,50,25}, Hs_[4]={112,56,28,14};
    int n=t>>2, l=t&3;
    float x=sm.px[n], y=sm.py[n];
    int iv=sm.iv[n];
    int W=Ws_[l], H=Hs_[l];
    float gx = (x * ((float)W/800.f)) / (W-1.f) * 2.f - 1.f;
    float gy = (y * ((float)H/448.f)) / (H-1.f) * 2.f - 1.f;
    gx=fminf(fmaxf(gx,-10.f),10.f); gy=fminf(fmaxf(gy,-10.f),10.f);
    if(iv){gx=-100.f;gy=-100.f;}
    float pxx=(gx+1.f)*0.5f*(W-1.f);
    float pyy=(gy+1.f)*0.5f*(H-1.f);
    float x0f=floorf(pxx), y0f=floorf(pyy);
    int x0=(int)x0f, y0=(int)y0f;
    float wx1=pxx-x0f, wy1=pyy-y0f, wx0=1.f-wx1, wy0=1.f-wy1;
    int vx0=(x0>=0)&(x0<W), vx1=(x0+1>=0)&(x0+1<W);
    int vy0=(y0>=0)&(y0<H), vy1=(y0+1>=0)&(y0+1<H);
    int cx0=min(max(x0,0),W-1), cx1=min(max(x0+1,0),W-1);
    int cy0=min(max(y0,0),H-1), cy1=min(max(y0+1,0),H-1);
    sm.off[t][0]=cy0*W+cx0; sm.wgt[t][0]=wx0*wy0*(float)(vx0&vy0);
    sm.off[t][1]=cy0*W+cx1; sm.wgt[t][1]=wx1*wy0*(float)(vx1&vy0);
    sm.off[t][2]=cy1*W+cx0; sm.wgt[t][2]=wx0*wy1*(float)(vx0&vy1);
    sm.off[t][3]=cy1*W+cx1; sm.wgt[t][3]=wx1*wy1*(float)(vx1&vy1);
  }
  __syncthreads();

  // phase 3: sampling — thread t = channel t, 6 cams x 4 levels x 4 corners
  {
    const void* fb[4]={f0,f1,f2,f3};
    const long HWs[4]={22400,5600,1400,350};
    #pragma unroll
    for(int n=0;n<NCAM;n++){
      int chan = (b*NCAM+n)*NC + t;
      float acc=0.f;
      #pragma unroll
      for(int l=0;l<4;l++){
        int u=n*4+l;
        long cb=(long)chan*HWs[l];
        const void* fp=fb[l];
        acc=fmaf(sm.wgt[u][0], ld1<F>(fp,cb+sm.off[u][0]), acc);
        acc=fmaf(sm.wgt[u][1], ld1<F>(fp,cb+sm.off[u][1]), acc);
        acc=fmaf(sm.wgt[u][2], ld1<F>(fp,cb+sm.off[u][2]), acc);
        acc=fmaf(sm.wgt[u][3], ld1<F>(fp,cb+sm.off[u][3]), acc);
      }
      sm.ms[n][t]=acc*0.25f;
    }
  }

  // phase 4: q projection (row t of Wq) — vectorized
  float qv = 0.f;
  {
    long rb=(long)t*NC;
    const f4* sq4=(const f4*)sm.q;
    #pragma unroll 8
    for(int k4=0;k4<NC/4;k4++){
      f4 wv=ld4<F>(Wq, rb+4*k4);
      f4 xv=sq4[k4];
      qv=fmaf(wv.x,xv.x,qv); qv=fmaf(wv.y,xv.y,qv);
      qv=fmaf(wv.z,xv.z,qv); qv=fmaf(wv.w,xv.w,qv);
    }
    qv += ld1<F>(bq,t);
  }
  __syncthreads();   // sm.ms ready

  // phase 5: v projection + max over cameras
  float ac[NCAM];
  #pragma unroll
  for(int n=0;n<NCAM;n++) ac[n]=0.f;
  {
    long rb=(long)t*NC;
    #pragma unroll 4
    for(int k4=0;k4<NC/4;k4++){
      f4 wv=ld4<F>(Wv, rb+4*k4);
      #pragma unroll
      for(int n=0;n<NCAM;n++){
        f4 mv=((const f4*)sm.ms[n])[k4];
        ac[n]=fmaf(wv.x,mv.x,ac[n]); ac[n]=fmaf(wv.y,mv.y,ac[n]);
        ac[n]=fmaf(wv.z,mv.z,ac[n]); ac[n]=fmaf(wv.w,mv.w,ac[n]);
      }
    }
  }
  float sv = ac[0];
  #pragma unroll
  for(int n=1;n<NCAM;n++) sv = fmaxf(sv, ac[n]);
  sv += ld1<F>(bv,t);

  sm.fus[t] = fmaxf(qv+sv, 0.f) + qv;
  __syncthreads();

  // phase 6: output projection
  float o = 0.f;
  {
    long rb=(long)t*NC;
    const f4* sf4=(const f4*)sm.fus;
    #pragma unroll 8
    for(int k4=0;k4<NC/4;k4++){
      f4 wv=ld4<F>(Wo, rb+4*k4);
      f4 xv=sf4[k4];
      o=fmaf(wv.x,xv.x,o); o=fmaf(wv.y,xv.y,o);
      o=fmaf(wv.z,xv.z,o); o=fmaf(wv.w,xv.w,o);
    }
    o += ld1<F>(bo,t);
  }
  if (m) o = 0.f;
  out[(long)row*NC+t] = o;
}

__global__ __launch_bounds__(256,4) void fused_kernel(
    const void* query, const void* refpts, const void* intr,
    const void* f0, const void* f1, const void* f2, const void* f3,
    const void* Wq, const void* bq, const void* Wv, const void* bv,
    const void* Wo, const void* bo,
    const float* __restrict__ inv_ext, const int* __restrict__ mask_int,
    const int* __restrict__ flag, float* __restrict__ out){
  __shared__ SharedMem sm;
  if (*flag)
    fused_body<1>(query,refpts,intr,f0,f1,f2,f3,Wq,bq,Wv,bv,Wo,bo,inv_ext,mask_int,out,sm);
  else
    fused_body<0>(query,refpts,intr,f0,f1,f2,f3,Wq,bq,Wv,bv,Wo,bo,inv_ext,mask_int,out,sm);
}

extern "C" void kernel_launch(void* const* d_in, const int* in_sizes, int n_in,
                              void* d_out, int out_size, void* d_ws, size_t ws_size,
                              hipStream_t stream){
  const void* query  = d_in[0];
  const void* refpts = d_in[1];
  const unsigned char* mask_raw = (const unsigned char*)d_in[2];
  const void* intr   = d_in[3];
  const void* ext    = d_in[4];
  const void* f0     = d_in[5];
  const void* f1     = d_in[6];
  const void* f2     = d_in[7];
  const void* f3     = d_in[8];
  const void* Wq     = d_in[9];
  const void* bq     = d_in[10];
  const void* Wv     = d_in[11];
  const void* bv     = d_in[12];
  const void* Wo     = d_in[13];
  const void* bo     = d_in[14];

  char* ws = (char*)d_ws;
  float* inv_ext  = (float*)(ws + 0);       // 768 B
  int*   dflag    = (int*)  (ws + 1024);    // 4 B
  int*   mask_int = (int*)  (ws + 2048);    // 7200 B  (total <10 KB)

  hipLaunchKernelGGL(prep_kernel, dim3(1), dim3(256), 0, stream,
                     (const unsigned char*)refpts, ext, mask_raw, dflag, inv_ext, mask_int);
  hipLaunchKernelGGL(fused_kernel, dim3(NROW), dim3(256), 0, stream,
                     query, refpts, intr, f0, f1, f2, f3,
                     Wq, bq, Wv, bv, Wo, bo,
                     inv_ext, mask_int, dflag, (float*)d_out);
}

// Round 6
// 543.940 us; speedup vs baseline: 2.1565x; 1.2914x over previous
//
#include <hip/hip_runtime.h>
#include <hip/hip_bf16.h>
#include <math.h>

#define BB 2
#define NCAM 6
#define NQ 900
#define NC 256
#define BN (BB*NCAM)        // 12
#define NROW (BB*NQ)        // 1800

typedef float f4 __attribute__((ext_vector_type(4)));
typedef unsigned short u16x4 __attribute__((ext_vector_type(4)));

__device__ __forceinline__ float u2f(unsigned short u){
  union{unsigned int v; float fl;} x; x.v=((unsigned int)u)<<16; return x.fl;
}

template<int F>
__device__ __forceinline__ float ld1(const void* p, long i){
  if (F) return u2f(((const unsigned short*)p)[i]);
  return ((const float*)p)[i];
}
template<int F>
__device__ __forceinline__ f4 ld4(const void* p, long i){ // i = element index, %4==0
  if (F){
    u16x4 u = *(const u16x4*)((const unsigned short*)p + i);
    f4 r; r.x=u2f(u.x); r.y=u2f(u.y); r.z=u2f(u.z); r.w=u2f(u.w); return r;
  }
  return *(const f4*)((const float*)p + i);
}

// ---------------- prep: dtype sniff + mask normalize + extrinsic inverse ----------------
__global__ void prep_kernel(const unsigned char* __restrict__ refraw,
                            const void* __restrict__ ext,
                            const unsigned char* __restrict__ mask_raw,
                            int* __restrict__ flag_out,
                            float* __restrict__ inv_out,
                            int* __restrict__ mask_out){
  __shared__ int s_nonalign, s_gt1, s_bf, s_flag;
  int t = threadIdx.x;
  if (t==0){
    s_nonalign=0; s_gt1=0; s_bf=0;
    int cnt=0;
    for (int i=1;i<64;i+=4){
      unsigned char b = refraw[i];
      if (b>=0x30 && b<0x40) cnt++;
    }
    s_flag = (cnt>=12) ? 1 : 0;
    *flag_out = s_flag;
  }
  __syncthreads();
  int f_na=0, f_gt=0, f_bf=0;
  for (int i=t;i<NROW;i+=blockDim.x){
    unsigned char b = mask_raw[i];
    if ((i&3)!=0 && b!=0) f_na=1;
    if (b>1) f_gt=1;
    if ((i&3)==1 && b==0x3f) f_bf=1;
  }
  if (f_na) atomicOr(&s_nonalign,1);
  if (f_gt) atomicOr(&s_gt1,1);
  if (f_bf) atomicOr(&s_bf,1);
  __syncthreads();
  int fmt; // 0=int32, 1=uint8(bool), 2=bf16, 3=fp32
  if (!s_nonalign) fmt=0;
  else if (!s_gt1)  fmt=1;
  else              fmt = s_bf ? 2 : 3;
  for (int i=t;i<NROW;i+=blockDim.x){
    int v;
    if (fmt==0)      v = (((const int*)mask_raw)[i]            != 0);
    else if (fmt==1) v = (mask_raw[i]                          != 0);
    else if (fmt==2) v = (((const unsigned short*)mask_raw)[i] != 0);
    else             v = (((const float*)mask_raw)[i]          != 0.0f);
    mask_out[i]=v;
  }
  if (t < BN){
    int f = s_flag;
    double a[4][8];
    for(int i=0;i<4;i++){
      for(int j=0;j<4;j++) a[i][j] = (double)(f? u2f(((const unsigned short*)ext)[t*16+i*4+j])
                                               : ((const float*)ext)[t*16+i*4+j]);
      for(int j=0;j<4;j++) a[i][4+j] = (i==j)?1.0:0.0;
    }
    for(int col=0;col<4;col++){
      int piv=col; double best=fabs(a[col][col]);
      for(int r=col+1;r<4;r++){ double v=fabs(a[r][col]); if(v>best){best=v;piv=r;} }
      if(piv!=col) for(int j=0;j<8;j++){ double tmp=a[col][j]; a[col][j]=a[piv][j]; a[piv][j]=tmp; }
      double id = 1.0/a[col][col];
      for(int j=0;j<8;j++) a[col][j]*=id;
      for(int r=0;r<4;r++) if(r!=col){
        double fc=a[r][col];
        for(int j=0;j<8;j++) a[r][j]-=fc*a[col][j];
      }
    }
    for(int i=0;i<4;i++)for(int j=0;j<4;j++){
      float v=(float)a[i][4+j];
      if (isnan(v)) v=0.f;
      else if (isinf(v)) v = (v>0.f)?1e6f:-1e6f;
      inv_out[t*16+i*4+j]=v;
    }
  }
}

// ---------------- relayout: W[t][k] -> blk[k/4][t][4], fp32 ----------------
// lane-coalesced weight access in the hot loop: Wblk4[k4*256 + t] is a float4
__global__ __launch_bounds__(256) void relayout_kernel(
    const void* __restrict__ Wq, const void* __restrict__ Wv,
    const void* __restrict__ Wo, const int* __restrict__ flag,
    float* __restrict__ dst){
  int e = blockIdx.x*256 + threadIdx.x;   // 0 .. 3*65536-1
  int f = *flag;
  int mat = e >> 16;
  int i = e & 65535;
  int t = i >> 8, k = i & 255;
  const void* W = (mat==0)?Wq:((mat==1)?Wv:Wo);
  float v = f ? u2f(((const unsigned short*)W)[i]) : ((const float*)W)[i];
  dst[mat*65536 + (k>>2)*1024 + t*4 + (k&3)] = v;
}

// ---------------- fused kernel ----------------
struct SharedMem {
  float q[NC];
  float ms[NCAM][NC];
  float fus[NC];
  float px[NCAM], py[NCAM];
  int   iv[NCAM];
  int   off[NCAM*4][4];
  float wgt[NCAM*4][4];
};

// RL=1: weights from relaid fp32 blocked buffer; RL=0: direct (fallback)
template<int F, int RL>
__device__ __forceinline__ void fused_body(
    const void* __restrict__ query, const void* __restrict__ refpts,
    const void* __restrict__ intr,
    const void* __restrict__ f0, const void* __restrict__ f1,
    const void* __restrict__ f2, const void* __restrict__ f3,
    const void* __restrict__ Wq, const void* __restrict__ bq,
    const void* __restrict__ Wv, const void* __restrict__ bv,
    const void* __restrict__ Wo, const void* __restrict__ bo,
    const float* __restrict__ Wblk,
    const float* __restrict__ inv_ext, const int* __restrict__ mask_int,
    float* __restrict__ out, SharedMem& sm){
  int row = blockIdx.x;           // b*NQ + q
  int b = row/NQ;
  int t = threadIdx.x;
  int m = mask_int[row];

  const f4* Wq4 = (const f4*)(Wblk);
  const f4* Wv4 = (const f4*)(Wblk + 65536);
  const f4* Wo4 = (const f4*)(Wblk + 131072);

  // phase 1: stage query row; threads 0..5 project through camera t
  sm.q[t] = ld1<F>(query, (long)row*NC+t);
  if (t < NCAM){
    float h0 = ld1<F>(refpts,(long)row*3+0)*102.4f - 51.2f;
    float h1 = ld1<F>(refpts,(long)row*3+1)*102.4f - 51.2f;
    float h2 = ld1<F>(refpts,(long)row*3+2)*102.4f - 51.2f;
    if (m){ h0=-1000.f; h1=-1000.f; h2=-1000.f; }
    const float* M = inv_ext + (b*NCAM+t)*16;
    float c0 = M[0]*h0 + M[1]*h1 + M[2]*h2 + M[3];
    float c1 = M[4]*h0 + M[5]*h1 + M[6]*h2 + M[7];
    float c2 = M[8]*h0 + M[9]*h1 + M[10]*h2 + M[11];
    float depth = c2;
    if (isnan(depth)) depth = 10.f;
    else if (isinf(depth)) depth = (depth>0)?100.f:-100.f;
    int iv = (depth < 1.5f);
    float ds = fmaxf(depth, 1.5f);
    float pc0=c0/ds, pc1=c1/ds, pc2=c2/ds;
    long kb = (long)(b*NCAM+t)*9;
    float ix = ld1<F>(intr,kb+0)*pc0 + ld1<F>(intr,kb+1)*pc1 + ld1<F>(intr,kb+2)*pc2;
    float iy = ld1<F>(intr,kb+3)*pc0 + ld1<F>(intr,kb+4)*pc1 + ld1<F>(intr,kb+5)*pc2;
    sm.px[t] = fminf(fmaxf(ix,-3000.f),3000.f);
    sm.py[t] = fminf(fmaxf(iy,-3000.f),3000.f);
    sm.iv[t] = iv;
  }
  __syncthreads();

  // phase 2: threads 0..23 precompute per-(cam,level) corner offsets + weights
  if (t < NCAM*4){
    const int Ws_[4]={200,100,50,25}, Hs_[4]={112,56,28,14};
    int n=t>>2, l=t&3;
    float x=sm.px[n], y=sm.py[n];
    int iv=sm.iv[n];
    int W=Ws_[l], H=Hs_[l];
    float gx = (x * ((float)W/800.f)) / (W-1.f) * 2.f - 1.f;
    float gy = (y * ((float)H/448.f)) / (H-1.f) * 2.f - 1.f;
    gx=fminf(fmaxf(gx,-10.f),10.f); gy=fminf(fmaxf(gy,-10.f),10.f);
    if(iv){gx=-100.f;gy=-100.f;}
    float pxx=(gx+1.f)*0.5f*(W-1.f);
    float pyy=(gy+1.f)*0.5f*(H-1.f);
    float x0f=floorf(pxx), y0f=floorf(pyy);
    int x0=(int)x0f, y0=(int)y0f;
    float wx1=pxx-x0f, wy1=pyy-y0f, wx0=1.f-wx1, wy0=1.f-wy1;
    int vx0=(x0>=0)&(x0<W), vx1=(x0+1>=0)&(x0+1<W);
    int vy0=(y0>=0)&(y0<H), vy1=(y0+1>=0)&(y0+1<H);
    int cx0=min(max(x0,0),W-1), cx1=min(max(x0+1,0),W-1);
    int cy0=min(max(y0,0),H-1), cy1=min(max(y0+1,0),H-1);
    sm.off[t][0]=cy0*W+cx0; sm.wgt[t][0]=wx0*wy0*(float)(vx0&vy0);
    sm.off[t][1]=cy0*W+cx1; sm.wgt[t][1]=wx1*wy0*(float)(vx1&vy0);
    sm.off[t][2]=cy1*W+cx0; sm.wgt[t][2]=wx0*wy1*(float)(vx0&vy1);
    sm.off[t][3]=cy1*W+cx1; sm.wgt[t][3]=wx1*wy1*(float)(vx1&vy1);
  }
  __syncthreads();

  // phase 3: sampling — thread t = channel t, 6 cams x 4 levels x 4 corners
  {
    const void* fb[4]={f0,f1,f2,f3};
    const long HWs[4]={22400,5600,1400,350};
    #pragma unroll
    for(int n=0;n<NCAM;n++){
      int chan = (b*NCAM+n)*NC + t;
      float acc=0.f;
      #pragma unroll
      for(int l=0;l<4;l++){
        int u=n*4+l;
        long cb=(long)chan*HWs[l];
        const void* fp=fb[l];
        acc=fmaf(sm.wgt[u][0], ld1<F>(fp,cb+sm.off[u][0]), acc);
        acc=fmaf(sm.wgt[u][1], ld1<F>(fp,cb+sm.off[u][1]), acc);
        acc=fmaf(sm.wgt[u][2], ld1<F>(fp,cb+sm.off[u][2]), acc);
        acc=fmaf(sm.wgt[u][3], ld1<F>(fp,cb+sm.off[u][3]), acc);
      }
      sm.ms[n][t]=acc*0.25f;
    }
  }

  // phase 4: q projection (row t of Wq)
  float qv = 0.f;
  {
    const f4* sq4=(const f4*)sm.q;
    #pragma unroll 8
    for(int k4=0;k4<NC/4;k4++){
      f4 wv = RL ? Wq4[k4*256 + t] : ld4<F>(Wq, (long)t*NC + 4*k4);
      f4 xv = sq4[k4];
      qv=fmaf(wv.x,xv.x,qv); qv=fmaf(wv.y,xv.y,qv);
      qv=fmaf(wv.z,xv.z,qv); qv=fmaf(wv.w,xv.w,qv);
    }
    qv += ld1<F>(bq,t);
  }
  __syncthreads();   // sm.ms ready

  // phase 5: v projection + max over cameras
  float ac[NCAM];
  #pragma unroll
  for(int n=0;n<NCAM;n++) ac[n]=0.f;
  {
    #pragma unroll 4
    for(int k4=0;k4<NC/4;k4++){
      f4 wv = RL ? Wv4[k4*256 + t] : ld4<F>(Wv, (long)t*NC + 4*k4);
      #pragma unroll
      for(int n=0;n<NCAM;n++){
        f4 mv=((const f4*)sm.ms[n])[k4];
        ac[n]=fmaf(wv.x,mv.x,ac[n]); ac[n]=fmaf(wv.y,mv.y,ac[n]);
        ac[n]=fmaf(wv.z,mv.z,ac[n]); ac[n]=fmaf(wv.w,mv.w,ac[n]);
      }
    }
  }
  float sv = ac[0];
  #pragma unroll
  for(int n=1;n<NCAM;n++) sv = fmaxf(sv, ac[n]);
  sv += ld1<F>(bv,t);

  sm.fus[t] = fmaxf(qv+sv, 0.f) + qv;
  __syncthreads();

  // phase 6: output projection
  float o = 0.f;
  {
    const f4* sf4=(const f4*)sm.fus;
    #pragma unroll 8
    for(int k4=0;k4<NC/4;k4++){
      f4 wv = RL ? Wo4[k4*256 + t] : ld4<F>(Wo, (long)t*NC + 4*k4);
      f4 xv = sf4[k4];
      o=fmaf(wv.x,xv.x,o); o=fmaf(wv.y,xv.y,o);
      o=fmaf(wv.z,xv.z,o); o=fmaf(wv.w,xv.w,o);
    }
    o += ld1<F>(bo,t);
  }
  if (m) o = 0.f;
  out[(long)row*NC+t] = o;
}

template<int RL>
__global__ __launch_bounds__(256,4) void fused_kernel(
    const void* query, const void* refpts, const void* intr,
    const void* f0, const void* f1, const void* f2, const void* f3,
    const void* Wq, const void* bq, const void* Wv, const void* bv,
    const void* Wo, const void* bo, const float* __restrict__ Wblk,
    const float* __restrict__ inv_ext, const int* __restrict__ mask_int,
    const int* __restrict__ flag, float* __restrict__ out){
  __shared__ SharedMem sm;
  if (*flag)
    fused_body<1,RL>(query,refpts,intr,f0,f1,f2,f3,Wq,bq,Wv,bv,Wo,bo,Wblk,inv_ext,mask_int,out,sm);
  else
    fused_body<0,RL>(query,refpts,intr,f0,f1,f2,f3,Wq,bq,Wv,bv,Wo,bo,Wblk,inv_ext,mask_int,out,sm);
}

extern "C" void kernel_launch(void* const* d_in, const int* in_sizes, int n_in,
                              void* d_out, int out_size, void* d_ws, size_t ws_size,
                              hipStream_t stream){
  const void* query  = d_in[0];
  const void* refpts = d_in[1];
  const unsigned char* mask_raw = (const unsigned char*)d_in[2];
  const void* intr   = d_in[3];
  const void* ext    = d_in[4];
  const void* f0     = d_in[5];
  const void* f1     = d_in[6];
  const void* f2     = d_in[7];
  const void* f3     = d_in[8];
  const void* Wq     = d_in[9];
  const void* bq     = d_in[10];
  const void* Wv     = d_in[11];
  const void* bv     = d_in[12];
  const void* Wo     = d_in[13];
  const void* bo     = d_in[14];

  char* ws = (char*)d_ws;
  float* inv_ext  = (float*)(ws + 0);       // 768 B
  int*   dflag    = (int*)  (ws + 1024);    // 4 B
  int*   mask_int = (int*)  (ws + 2048);    // 7200 B
  float* Wblk     = (float*)(ws + 16384);   // 786432 B (3 x 256x256 fp32)

  hipLaunchKernelGGL(prep_kernel, dim3(1), dim3(256), 0, stream,
                     (const unsigned char*)refpts, ext, mask_raw, dflag, inv_ext, mask_int);

  bool relay = ws_size >= (size_t)(16384 + 786432);
  if (relay){
    hipLaunchKernelGGL(relayout_kernel, dim3(768), dim3(256), 0, stream,
                       Wq, Wv, Wo, dflag, Wblk);
    hipLaunchKernelGGL(fused_kernel<1>, dim3(NROW), dim3(256), 0, stream,
                       query, refpts, intr, f0, f1, f2, f3,
                       Wq, bq, Wv, bv, Wo, bo, Wblk,
                       inv_ext, mask_int, dflag, (float*)d_out);
  } else {
    hipLaunchKernelGGL(fused_kernel<0>, dim3(NROW), dim3(256), 0, stream,
                       query, refpts, intr, f0, f1, f2, f3,
                       Wq, bq, Wv, bv, Wo, bo, Wblk,
                       inv_ext, mask_int, dflag, (float*)d_out);
  }
}